// Round 8
// baseline (592.775 us; speedup 1.0000x reference)
//
#include <hip/hip_runtime.h>

// Tanh-RNN: B=8192, T=2048, I=2, H=20, FC(H->1) on last h.
// Round 8: R7 (j-split, 8 lanes/row, 1024 waves = 1/SIMD, DPP-butterfly
// h-allgather, zero LDS) + packed math: the 72-FMA dot and 3 init FMAs are
// expressed as __builtin_elementwise_fma on float ext_vector_type(2)
// (llvm.fma.v2f32 -> v_pk_fma_f32 on gfx950), halving dot issue 144->72 cyc.
// pk_fma is IEEE FMA per component in the same order -> bit-identical output.
// DPP butterfly unchanged from R7 (verified): xor4 masked row_shl/shr:4,
// xor1 quad_perm 0xB1, xor2 quad_perm 0x4E; slot triplets g' = g ^ M[s/3],
// M = {0,4,1,5,2,6,3,7}; weights pre-permuted to slot order.

#define T_STEPS 2048
#define B_ROWS  8192
#define NCHUNK  (T_STEPS / 8)

typedef float v2f __attribute__((ext_vector_type(2)));

__device__ __forceinline__ v2f mkv2(float a, float b) {
    v2f r; r.x = a; r.y = b; return r;
}

__device__ __forceinline__ float tanh_fast(float a) {
    // tanh(a) = 1 - 2/(exp(2a)+1); exp(2a)=exp2(a*2*log2e). Saturates correctly.
    float e = __builtin_amdgcn_exp2f(a * 2.8853900817779268f);
    float r = __builtin_amdgcn_rcpf(e + 1.0f);
    return fmaf(-2.0f, r, 1.0f);
}

// ---- DPP cross-lane (within a 16-lane DPP row; octet = aligned half-row) ----
#define XOR1_CTRL 0xB1   // quad_perm(1,0,3,2): lane^1
#define XOR2_CTRL 0x4E   // quad_perm(2,3,0,1): lane^2

template <int CTRL>
__device__ __forceinline__ float dpp_full(float v) {
    return __int_as_float(__builtin_amdgcn_update_dpp(
        0, __float_as_int(v), CTRL, 0xF, 0xF, true));
}

// lane^4 within each 8-lane octet (16-lane DPP row holds 2 octets):
//   lanes 0-3, 8-11  (banks 0,2): need src L+4 -> row_shl:4 (0x104)
//   lanes 4-7, 12-15 (banks 1,3): need src L-4 -> row_shr:4 (0x114)
__device__ __forceinline__ float dpp_xor4(float v) {
    int t = __builtin_amdgcn_update_dpp(__float_as_int(v), __float_as_int(v),
                                        0x104 /*row_shl:4*/, 0xF, 0x5, false);
    t = __builtin_amdgcn_update_dpp(t, __float_as_int(v),
                                    0x114 /*row_shr:4*/, 0xF, 0xA, false);
    return __int_as_float(t);
}

__global__ __launch_bounds__(64, 1) void rnn_fused(
    const float* __restrict__ x,      // [B, T, 2]
    const float* __restrict__ W_ih,   // [20, 2]
    const float* __restrict__ W_hh,   // [20, 20]
    const float* __restrict__ b_ih,   // [20]
    const float* __restrict__ b_hh,   // [20]
    const float* __restrict__ fc_w,   // [1, 20]
    const float* __restrict__ fc_b,   // [1]
    float* __restrict__ out)          // [8192] out, then [8192*20] h_state
{
    const int lane = threadIdx.x & 63;
    const int g    = lane & 7;        // owns j = 3g..3g+2
    const int r    = lane >> 3;       // row within wave
    const int row  = blockIdx.x * 8 + r;

    const int M[8] = {0, 4, 1, 5, 2, 6, 3, 7};

    v2f   W2[3][12];                  // pair p covers slots 2p, 2p+1
    v2f   wib[3], bini[3];            // (wi0,wi1), (bsum,0)
    float fcw[3];
#pragma unroll
    for (int jj = 0; jj < 3; ++jj) {
        const int j = 3 * g + jj;
        const bool v = (j < 20);
#pragma unroll
        for (int p = 0; p < 12; ++p) {
            float wv[2];
#pragma unroll
            for (int h = 0; h < 2; ++h) {
                const int slot = 2 * p + h;
                const int k = 3 * (g ^ M[slot / 3]) + (slot % 3);
                wv[h] = (v && k < 20) ? W_hh[j * 20 + k] : 0.0f;
            }
            W2[jj][p] = mkv2(wv[0], wv[1]);
        }
        wib[jj]  = mkv2(v ? W_ih[j * 2 + 0] : 0.0f,
                        v ? W_ih[j * 2 + 1] : 0.0f);
        bini[jj] = mkv2(v ? (b_ih[j] + b_hh[j]) : 0.0f, 0.0f);
        fcw[jj]  = v ? fc_w[j] : 0.0f;
    }

    v2f hp[12];                       // gathered h, butterfly slot order, paired
#pragma unroll
    for (int i = 0; i < 12; ++i) hp[i] = mkv2(0.0f, 0.0f);
    float hn0 = 0.0f, hn1 = 0.0f, hn2 = 0.0f;

    auto step = [&](v2f xp) {
        v2f c0 = __builtin_elementwise_fma(xp, wib[0], bini[0]);
        v2f c1 = __builtin_elementwise_fma(xp, wib[1], bini[1]);
        v2f c2 = __builtin_elementwise_fma(xp, wib[2], bini[2]);
#pragma unroll
        for (int p = 0; p < 12; ++p) {
            c0 = __builtin_elementwise_fma(hp[p], W2[0][p], c0);
            c1 = __builtin_elementwise_fma(hp[p], W2[1][p], c1);
            c2 = __builtin_elementwise_fma(hp[p], W2[2][p], c2);
        }
        hn0 = tanh_fast(c0.x + c0.y);
        hn1 = tanh_fast(c1.x + c1.y);
        hn2 = tanh_fast(c2.x + c2.y);
        // ---- DPP butterfly allgather (24 DPP ops, no LDS) ----
        const float s0 = hn0, s1 = hn1, s2 = hn2;
        const float s3 = dpp_xor4(s0);
        const float s4 = dpp_xor4(s1);
        const float s5 = dpp_xor4(s2);
        const float s6  = dpp_full<XOR1_CTRL>(s0);
        const float s7  = dpp_full<XOR1_CTRL>(s1);
        const float s8  = dpp_full<XOR1_CTRL>(s2);
        const float s9  = dpp_full<XOR1_CTRL>(s3);
        const float s10 = dpp_full<XOR1_CTRL>(s4);
        const float s11 = dpp_full<XOR1_CTRL>(s5);
        const float s12 = dpp_full<XOR2_CTRL>(s0);
        const float s13 = dpp_full<XOR2_CTRL>(s1);
        const float s14 = dpp_full<XOR2_CTRL>(s2);
        const float s15 = dpp_full<XOR2_CTRL>(s3);
        const float s16 = dpp_full<XOR2_CTRL>(s4);
        const float s17 = dpp_full<XOR2_CTRL>(s5);
        const float s18 = dpp_full<XOR2_CTRL>(s6);
        const float s19 = dpp_full<XOR2_CTRL>(s7);
        const float s20 = dpp_full<XOR2_CTRL>(s8);
        const float s21 = dpp_full<XOR2_CTRL>(s9);
        const float s22 = dpp_full<XOR2_CTRL>(s10);
        const float s23 = dpp_full<XOR2_CTRL>(s11);
        hp[0]  = mkv2(s0,  s1);
        hp[1]  = mkv2(s2,  s3);
        hp[2]  = mkv2(s4,  s5);
        hp[3]  = mkv2(s6,  s7);
        hp[4]  = mkv2(s8,  s9);
        hp[5]  = mkv2(s10, s11);
        hp[6]  = mkv2(s12, s13);
        hp[7]  = mkv2(s14, s15);
        hp[8]  = mkv2(s16, s17);
        hp[9]  = mkv2(s18, s19);
        hp[10] = mkv2(s20, s21);
        hp[11] = mkv2(s22, s23);
    };

    // x: per 8-step chunk, 4 float4 per lane (octet shares the cacheline, L1
    // broadcast); double-buffered one chunk ahead. (x,y)/(z,w) of a dwordx4
    // load are already aligned VGPR pairs -> xp pair build is free.
    const float4* xq = (const float4*)(x + (size_t)row * (T_STEPS * 2));
    float4 q[4], qn[4];
#pragma unroll
    for (int i = 0; i < 4; ++i) q[i] = xq[i];

    for (int c = 0; c < NCHUNK; ++c) {
        const int cn = (c + 1 < NCHUNK) ? (c + 1) : c;   // clamped dummy prefetch
#pragma unroll
        for (int i = 0; i < 4; ++i) qn[i] = xq[4 * cn + i];

        step(mkv2(q[0].x, q[0].y)); step(mkv2(q[0].z, q[0].w));
        step(mkv2(q[1].x, q[1].y)); step(mkv2(q[1].z, q[1].w));
        step(mkv2(q[2].x, q[2].y)); step(mkv2(q[2].z, q[2].w));
        step(mkv2(q[3].x, q[3].y)); step(mkv2(q[3].z, q[3].w));

#pragma unroll
        for (int i = 0; i < 4; ++i) q[i] = qn[i];
    }

    // ---- epilogue ----
    // h_state: [1, B, H] flat at offset B_ROWS; lane stores its own 3 j's
    {
        const int j0 = 3 * g;
        float* hs = out + B_ROWS + (size_t)row * 20;
        if (j0 + 0 < 20) hs[j0 + 0] = hn0;
        if (j0 + 1 < 20) hs[j0 + 1] = hn1;
        if (j0 + 2 < 20) hs[j0 + 2] = hn2;
    }
    // FC: per-lane partial over own j's, octet tree-reduce via DPP butterfly
    {
        float p = hn0 * fcw[0];
        p = fmaf(hn1, fcw[1], p);
        p = fmaf(hn2, fcw[2], p);
        p += dpp_full<XOR1_CTRL>(p);
        p += dpp_full<XOR2_CTRL>(p);
        p += dpp_xor4(p);
        if (g == 0) out[row] = p + fc_b[0];
    }
}

extern "C" void kernel_launch(void* const* d_in, const int* in_sizes, int n_in,
                              void* d_out, int out_size, void* d_ws, size_t ws_size,
                              hipStream_t stream) {
    const float* x    = (const float*)d_in[0];
    const float* W_ih = (const float*)d_in[1];
    const float* W_hh = (const float*)d_in[2];
    const float* b_ih = (const float*)d_in[3];
    const float* b_hh = (const float*)d_in[4];
    const float* fc_w = (const float*)d_in[5];
    const float* fc_b = (const float*)d_in[6];
    float* out = (float*)d_out;

    // 1024 blocks x 64 threads: 1 wave/block, 8 rows/wave -> 1 wave/SIMD
    rnn_fused<<<1024, 64, 0, stream>>>(x, W_ih, W_hh, b_ih, b_hh, fc_w, fc_b, out);
}